// Round 7
// baseline (176.609 us; speedup 1.0000x reference)
//
#include <hip/hip_runtime.h>
#include <math.h>

// Problem constants (B,S,D,H,PD = 64,256,256,8,8)
#define BB 64
#define SS 256
#define DD 256
#define HH 8
#define HDIM 32
#define MROWS (BB*SS)   // 16384

typedef unsigned short u16;
typedef unsigned int u32;
typedef _Float16 f16;
typedef __attribute__((ext_vector_type(8))) _Float16 half8;  // 4 VGPR MFMA frag
typedef __attribute__((ext_vector_type(16))) float f32x16;   // 32x32 MFMA acc

union U4H8 { uint4 u; half8 h; u16 s[8]; };

__device__ __forceinline__ u16 f16b(float a) {               // RNE f32->f16
    f16 h = (f16)a; return __builtin_bit_cast(u16, h);
}
__device__ __forceinline__ u32 pk_rne(float a, float b) {
    return (u32)f16b(a) | ((u32)f16b(b) << 16);
}
// RTZ-split: hw = pkrtz(a,b); lw captures residual exactly (err ~2^-21)
__device__ __forceinline__ void pksplit2(float a, float b, u32& hw, u32& lw) {
    auto h = __builtin_amdgcn_cvt_pkrtz(a, b);
    hw = __builtin_bit_cast(u32, h);
    auto l = __builtin_amdgcn_cvt_pkrtz(a - (float)h[0], b - (float)h[1]);
    lw = __builtin_bit_cast(u32, l);
}
__device__ __forceinline__ void split8f(const float* e, uint4& h4, uint4& l4) {
    pksplit2(e[0], e[1], h4.x, l4.x);
    pksplit2(e[2], e[3], h4.y, l4.y);
    pksplit2(e[4], e[5], h4.z, l4.z);
    pksplit2(e[6], e[7], h4.w, l4.w);
}
__device__ __forceinline__ f32x16 mfma16f(half8 a, half8 b, f32x16 c) {
    return __builtin_amdgcn_mfma_f32_32x32x16_f16(a, b, c, 0, 0, 0);
}

// ---------------------------------------------------------------------------
// Weight convert: stack [Wq;Wk;Wv;Wo] (1024x256 fp32) -> single fp16 WH.
// ---------------------------------------------------------------------------
__global__ __launch_bounds__(256)
void wconv(const float* __restrict__ Wq, const float* __restrict__ Wk,
           const float* __restrict__ Wv, const float* __restrict__ Wo,
           u16* __restrict__ WH) {
    const int bx = blockIdx.x;                  // 0..255, 64 blocks per weight
    const int sel = bx >> 6;
    const float* src = (sel == 0) ? Wq : (sel == 1) ? Wk : (sel == 2) ? Wv : Wo;
    const int i = (bx & 63) * 1024 + threadIdx.x * 4;
    float4 v = *reinterpret_cast<const float4*>(src + i);
    *reinterpret_cast<uint2*>(WH + (size_t)sel * 65536 + i) =
        make_uint2(pk_rne(v.x, v.y), pk_rne(v.z, v.w));
}

// ---------------------------------------------------------------------------
// x -> split fp16 planes Xh, Xl (exact to ~2^-21 rel)
// ---------------------------------------------------------------------------
__global__ __launch_bounds__(256)
void xsplit(const float* __restrict__ x, u16* __restrict__ Xh,
            u16* __restrict__ Xl) {
    const size_t i = ((size_t)blockIdx.x * 256 + threadIdx.x) * 8;
    float4 a = *reinterpret_cast<const float4*>(x + i);
    float4 b = *reinterpret_cast<const float4*>(x + i + 4);
    float e[8] = {a.x,a.y,a.z,a.w,b.x,b.y,b.z,b.w};
    uint4 h4, l4;
    split8f(e, h4, l4);
    *reinterpret_cast<uint4*>(Xh + i) = h4;
    *reinterpret_cast<uint4*>(Xl + i) = l4;
}

// ---------------------------------------------------------------------------
// fp16 MFMA GEMM on pre-split planes: C = A @ W^T via Ah*W + Al*W.
// BM=128, BN=128, BK=32, 4 waves x 64x64.  A copy-staged u16 -> LDS
// (stride-40 rows).  W frags from global (L2-resident).
// MODE 1 (qkv): bx in [0,6): sel=bx>>1 -> Q (split planes) / K / V (single).
// MODE 0 (out): fp32 C + bias.
// ---------------------------------------------------------------------------
template<int MODE>
__global__ __launch_bounds__(256, 3)
void gemm_mfma(const u16* __restrict__ AH, const u16* __restrict__ AL,
               const u16* __restrict__ WH, const float* __restrict__ bias,
               float* __restrict__ Cf, u16* __restrict__ Ph0,
               u16* __restrict__ Pl0, u16* __restrict__ Ph1,
               u16* __restrict__ Ph2, int wbase) {
    __shared__ u16 Ah[128*40], Al[128*40];

    const int tid = threadIdx.x;
    const int lane = tid & 63, wv = tid >> 6;
    const int wm = wv >> 1, wn = wv & 1;
    const int hh = lane >> 5, ln = lane & 31;
    const int bx = blockIdx.x, m0 = blockIdx.y * 128;

    int sel = 0, n0, nstack0;
    if (MODE == 1) {
        sel = bx >> 1;
        n0 = (bx & 1) * 128;
        nstack0 = bx * 128;
    } else {
        n0 = bx * 128; nstack0 = wbase + bx * 128;
    }

    f32x16 acc[2][2];
    #pragma unroll
    for (int i = 0; i < 2; i++)
        #pragma unroll
        for (int j = 0; j < 2; j++)
            #pragma unroll
            for (int r = 0; r < 16; r++) acc[i][j][r] = 0.f;

    const int g0 = tid, g1 = 256 + tid;
    const int r0 = g0 >> 2, c80 = g0 & 3;
    const int r1 = g1 >> 2, c81 = g1 & 3;
    const u16* pH0 = AH + (size_t)(m0 + r0) * 256 + c80 * 8;
    const u16* pL0 = AL + (size_t)(m0 + r0) * 256 + c80 * 8;
    const u16* pH1 = AH + (size_t)(m0 + r1) * 256 + c81 * 8;
    const u16* pL1 = AL + (size_t)(m0 + r1) * 256 + c81 * 8;

    const u16* WHrow = WH + (size_t)(nstack0 + wn*64 + ln) * 256;

    uint4 h0 = *reinterpret_cast<const uint4*>(pH0);
    uint4 l0 = *reinterpret_cast<const uint4*>(pL0);
    uint4 h1 = *reinterpret_cast<const uint4*>(pH1);
    uint4 l1 = *reinterpret_cast<const uint4*>(pL1);

    #pragma unroll
    for (int s = 0; s < 8; s++) {
        const int kb = s * 32;
        *reinterpret_cast<uint4*>(&Ah[r0*40 + c80*8]) = h0;
        *reinterpret_cast<uint4*>(&Al[r0*40 + c80*8]) = l0;
        *reinterpret_cast<uint4*>(&Ah[r1*40 + c81*8]) = h1;
        *reinterpret_cast<uint4*>(&Al[r1*40 + c81*8]) = l1;
        __syncthreads();
        if (s < 7) {
            h0 = *reinterpret_cast<const uint4*>(pH0 + kb + 32);
            l0 = *reinterpret_cast<const uint4*>(pL0 + kb + 32);
            h1 = *reinterpret_cast<const uint4*>(pH1 + kb + 32);
            l1 = *reinterpret_cast<const uint4*>(pL1 + kb + 32);
        }

        U4H8 wf[2][2];                          // [tn][ks]
        #pragma unroll
        for (int tn = 0; tn < 2; tn++)
            #pragma unroll
            for (int ks = 0; ks < 2; ks++)
                wf[tn][ks].u = *reinterpret_cast<const uint4*>(
                    WHrow + (size_t)tn*32*256 + kb + ks*16 + hh*8);
        U4H8 afh[2][2], afl[2][2];              // [tm][ks]
        #pragma unroll
        for (int tm = 0; tm < 2; tm++)
            #pragma unroll
            for (int ks = 0; ks < 2; ks++) {
                const int el = (wm*64 + tm*32 + ln)*40 + ks*16 + hh*8;
                afh[tm][ks].u = *reinterpret_cast<const uint4*>(&Ah[el]);
                afl[tm][ks].u = *reinterpret_cast<const uint4*>(&Al[el]);
            }
        __builtin_amdgcn_s_setprio(1);
        #pragma unroll
        for (int tm = 0; tm < 2; tm++)
            #pragma unroll
            for (int tn = 0; tn < 2; tn++)
                #pragma unroll
                for (int ks = 0; ks < 2; ks++) {
                    acc[tm][tn] = mfma16f(afh[tm][ks].h, wf[tn][ks].h, acc[tm][tn]);
                    acc[tm][tn] = mfma16f(afl[tm][ks].h, wf[tn][ks].h, acc[tm][tn]);
                }
        __builtin_amdgcn_s_setprio(0);
        __syncthreads();
    }

    #pragma unroll
    for (int tm = 0; tm < 2; tm++)
        #pragma unroll
        for (int tn = 0; tn < 2; tn++) {
            const int col = n0 + wn*64 + tn*32 + ln;
            const int mb = m0 + wm*64 + tm*32;
            if (MODE == 0) {
                const float bv = bias[col];
                #pragma unroll
                for (int r = 0; r < 16; r++) {
                    const int mm = mb + (r&3) + 8*(r>>2) + 4*hh;
                    Cf[(size_t)mm*256 + col] = acc[tm][tn][r] + bv;
                }
            } else if (sel == 0) {              // Q: split planes
                #pragma unroll
                for (int rp = 0; rp < 8; rp++) {
                    const int r = 2*rp;
                    const int mm = mb + (r&3) + 8*(r>>2) + 4*hh;
                    u32 hw, lw;
                    pksplit2(acc[tm][tn][r], acc[tm][tn][r+1], hw, lw);
                    Ph0[(size_t)mm*256 + col]     = (u16)hw;
                    Ph0[(size_t)(mm+1)*256 + col] = (u16)(hw >> 16);
                    Pl0[(size_t)mm*256 + col]     = (u16)lw;
                    Pl0[(size_t)(mm+1)*256 + col] = (u16)(lw >> 16);
                }
            } else {                            // K or V: single fp16
                u16* P = (sel == 1) ? Ph1 : Ph2;
                #pragma unroll
                for (int r = 0; r < 16; r++) {
                    const int mm = mb + (r&3) + 8*(r>>2) + 4*hh;
                    P[(size_t)mm*256 + col] = f16b(acc[tm][tn][r]);
                }
            }
        }
}

// ---------------------------------------------------------------------------
// Pos-MLP: e[b,h,s] = p[b,s,:]·head_w[h,:].  head_b and the e_s term cancel
// in softmax over t -> pos_attn = softmax_t(-e_t), s-independent.
// ---------------------------------------------------------------------------
__global__ __launch_bounds__(256)
void pos_kernel(const float* __restrict__ pos, const float* __restrict__ w1,
                const float* __restrict__ b1, const float* __restrict__ w2,
                const float* __restrict__ b2, const float* __restrict__ hw,
                float* __restrict__ E) {
    __shared__ float sw1[64], sb1[8], sw2[256], sb2[32], shw[256];
    const int tid = threadIdx.x;
    if (tid < 64)  sw1[tid] = w1[tid];
    if (tid < 8)   sb1[tid] = b1[tid];
    sw2[tid] = w2[tid];
    if (tid < 32)  sb2[tid] = b2[tid];
    shw[tid] = hw[tid];
    __syncthreads();

    const int row = blockIdx.x * 256 + tid;
    float pv[8];
    float4 p0 = *reinterpret_cast<const float4*>(pos + (size_t)row * 8);
    float4 p1 = *reinterpret_cast<const float4*>(pos + (size_t)row * 8 + 4);
    pv[0]=p0.x; pv[1]=p0.y; pv[2]=p0.z; pv[3]=p0.w;
    pv[4]=p1.x; pv[5]=p1.y; pv[6]=p1.z; pv[7]=p1.w;

    float h1[8];
    #pragma unroll
    for (int j = 0; j < 8; j++) {
        float a = sb1[j];
        #pragma unroll
        for (int i = 0; i < 8; i++) a = fmaf(pv[i], sw1[j*8+i], a);
        h1[j] = fmaxf(a, 0.f);
    }
    float p[32];
    #pragma unroll
    for (int c = 0; c < 32; c++) {
        float a = sb2[c];
        #pragma unroll
        for (int j = 0; j < 8; j++) a = fmaf(h1[j], sw2[c*8+j], a);
        p[c] = a;
    }
    const int b = row >> 8, s = row & 255;
    #pragma unroll
    for (int h = 0; h < 8; h++) {
        float e = 0.f;
        #pragma unroll
        for (int c = 0; c < 32; c++) e = fmaf(p[c], shw[h*32+c], e);
        E[((size_t)(b*8 + h) << 8) + s] = e;
    }
}

// ---------------------------------------------------------------------------
// posv: per (b,h), normalized pos-attention vector
// PVn[bh][d] = (sum_t exp(-e_t) V[t][d]) / (sum_t exp(-e_t))
// ---------------------------------------------------------------------------
__global__ __launch_bounds__(256)
void posv(const float* __restrict__ E, const u16* __restrict__ Vh,
          float* __restrict__ PVn) {
    __shared__ float ws[256];
    __shared__ float red[4];
    __shared__ float pvp[8][33];
    const int tid = threadIdx.x;
    const int bh = blockIdx.x, b = bh >> 3, h = bh & 7;

    float w = __expf(-E[((size_t)bh << 8) + tid]);
    ws[tid] = w;
    float v = w;
    #pragma unroll
    for (int off = 32; off > 0; off >>= 1) v += __shfl_down(v, off);
    if ((tid & 63) == 0) red[tid >> 6] = v;
    __syncthreads();
    const float psum = red[0] + red[1] + red[2] + red[3];

    const int d = tid & 31, ch = tid >> 5;
    float acc = 0.f;
    #pragma unroll
    for (int i = 0; i < 32; i++) {
        const int t = ch*32 + i;
        f16 vv = __builtin_bit_cast(f16, Vh[(((size_t)b*256 + t) << 8) + h*32 + d]);
        acc = fmaf(ws[t], (float)vv, acc);
    }
    pvp[ch][d] = acc;
    __syncthreads();
    if (tid < 32) {
        float s = 0.f;
        #pragma unroll
        for (int i = 0; i < 8; i++) s += pvp[i][tid];
        PVn[bh*32 + tid] = s / psum;
    }
}

// ---------------------------------------------------------------------------
// fp16 MFMA attention.  Grid 1024: block = (b,h, half of S).  4 waves, each
// one 32-row q-tile.  K,V staged as u16 copies (no conversion); Q read as
// pre-split hi/lo frags; O written as split planes.  LDS ~37.6KB -> 4 blk/CU.
// S^T = mfma(K,Q); P frag from C-regs via pack + shfl_xor(32) + select;
// O^T = mfma(Vt, P).
// ---------------------------------------------------------------------------
__global__ __launch_bounds__(256, 4)
void attn_kernel(const u16* __restrict__ Qh, const u16* __restrict__ Ql,
                 const u16* __restrict__ Kh, const u16* __restrict__ Vh,
                 const float* __restrict__ PVn, const float* __restrict__ gate,
                 u16* __restrict__ Oh, u16* __restrict__ Ol) {
    __shared__ u16 Ks[256*40];       // f16 bits, rows of 32, pad to 40
    __shared__ u16 Vt[32*264];       // [d][t] rows pad to 264
    __shared__ float sPV[32];

    const int tid = threadIdx.x;
    const int bid = blockIdx.x;
    const int bh = bid >> 1, hb = bid & 1;
    const int b = bh >> 3, h = bh & 7;
    const size_t rbase = (size_t)b * 256;
    const int cbase = h * 32;
    const float SCALE = 0.17677669529663687f;    // 1/sqrt(32)

    // ---- stage K rows + V^T (pure copies) ---------------------------------
    {
        const int t = tid;
        const u16* kr = Kh + ((rbase + t) << 8) + cbase;
        const u16* vr = Vh + ((rbase + t) << 8) + cbase;
        #pragma unroll
        for (int c = 0; c < 4; c++)
            *reinterpret_cast<uint4*>(&Ks[t*40 + c*8]) =
                *reinterpret_cast<const uint4*>(kr + c*8);
        U4H8 vv[4];
        #pragma unroll
        for (int c = 0; c < 4; c++)
            vv[c].u = *reinterpret_cast<const uint4*>(vr + c*8);
        #pragma unroll
        for (int c = 0; c < 4; c++)
            #pragma unroll
            for (int j = 0; j < 8; j++)
                Vt[(c*8+j)*264 + t] = vv[c].s[j];
        if (tid < 32) sPV[tid] = PVn[bh*32 + tid];
    }
    __syncthreads();

    const int lane = tid & 63, wv = tid >> 6;
    const int hh2 = lane >> 5, lq = lane & 31;
    const int q0 = hb*128 + wv*32;

    // Q fragments: pre-split hi/lo, direct uint4 loads
    U4H8 qh[2], ql[2];
    {
        const u16* qrh = Qh + ((rbase + q0 + lq) << 8) + cbase;
        const u16* qrl = Ql + ((rbase + q0 + lq) << 8) + cbase;
        #pragma unroll
        for (int ks = 0; ks < 2; ks++) {
            qh[ks].u = *reinterpret_cast<const uint4*>(qrh + ks*16 + hh2*8);
            ql[ks].u = *reinterpret_cast<const uint4*>(qrl + ks*16 + hh2*8);
        }
    }

    f32x16 acco;
    #pragma unroll
    for (int r = 0; r < 16; r++) acco[r] = 0.f;
    float rowsum = 0.f;

    #pragma unroll
    for (int tt = 0; tt < 8; tt++) {
        f32x16 accs;
        #pragma unroll
        for (int r = 0; r < 16; r++) accs[r] = 0.f;
        const int trow = tt*32 + lq;
        __builtin_amdgcn_s_setprio(1);
        #pragma unroll
        for (int ks = 0; ks < 2; ks++) {
            U4H8 kf;
            kf.u = *reinterpret_cast<const uint4*>(&Ks[trow*40 + ks*16 + hh2*8]);
            accs = mfma16f(kf.h, qh[ks].h, accs);
            accs = mfma16f(kf.h, ql[ks].h, accs);
        }
        __builtin_amdgcn_s_setprio(0);
        // P = exp(S*scale): split hi+lo fp16, packed
        u32 PH[8], PL[8];
        #pragma unroll
        for (int j = 0; j < 8; j++) {
            float p0 = __expf(accs[2*j]   * SCALE);
            float p1 = __expf(accs[2*j+1] * SCALE);
            rowsum += p0 + p1;
            pksplit2(p0, p1, PH[j], PL[j]);
        }
        // PV: B-frag from C-regs via shfl_xor(32) half-swap + select
        #pragma unroll
        for (int ks = 0; ks < 2; ks++) {
            u32 HA0 = PH[ks*4+0], HA1 = PH[ks*4+1];
            u32 HB0 = PH[ks*4+2], HB1 = PH[ks*4+3];
            u32 LA0 = PL[ks*4+0], LA1 = PL[ks*4+1];
            u32 LB0 = PL[ks*4+2], LB1 = PL[ks*4+3];
            u32 XA0 = (u32)__shfl_xor((int)HA0, 32);
            u32 XA1 = (u32)__shfl_xor((int)HA1, 32);
            u32 XB0 = (u32)__shfl_xor((int)HB0, 32);
            u32 XB1 = (u32)__shfl_xor((int)HB1, 32);
            u32 YA0 = (u32)__shfl_xor((int)LA0, 32);
            u32 YA1 = (u32)__shfl_xor((int)LA1, 32);
            u32 YB0 = (u32)__shfl_xor((int)LB0, 32);
            u32 YB1 = (u32)__shfl_xor((int)LB1, 32);
            U4H8 bhf, blf, vf;
            bhf.u = make_uint4(hh2 ? XB0 : HA0, hh2 ? XB1 : HA1,
                               hh2 ? HB0 : XA0, hh2 ? HB1 : XA1);
            blf.u = make_uint4(hh2 ? YB0 : LA0, hh2 ? YB1 : LA1,
                               hh2 ? LB0 : YA0, hh2 ? LB1 : YA1);
            vf.u = *reinterpret_cast<const uint4*>(
                &Vt[lq*264 + tt*32 + ks*16 + hh2*8]);
            __builtin_amdgcn_s_setprio(1);
            acco = mfma16f(vf.h, bhf.h, acco);
            acco = mfma16f(vf.h, blf.h, acco);
            __builtin_amdgcn_s_setprio(0);
        }
    }

    rowsum += __shfl_xor(rowsum, 32);
    const float g = 1.f / (1.f + __expf(-gate[h]));
    const float c1 = (1.f - g) / rowsum;
    u16* ohp = Oh + ((rbase + q0 + lq) << 8) + cbase;
    u16* olp = Ol + ((rbase + q0 + lq) << 8) + cbase;
    #pragma unroll
    for (int rp = 0; rp < 8; rp++) {
        const int r = 2*rp;
        const int d0 = (r & 3) + 8*(r >> 2) + 4*hh2;
        float o0 = c1 * acco[r]   + g * sPV[d0];
        float o1 = c1 * acco[r+1] + g * sPV[d0+1];
        u32 hw, lw;
        pksplit2(o0, o1, hw, lw);
        *reinterpret_cast<u32*>(ohp + d0) = hw;
        *reinterpret_cast<u32*>(olp + d0) = lw;
    }
}

// ---------------------------------------------------------------------------
extern "C" void kernel_launch(void* const* d_in, const int* in_sizes, int n_in,
                              void* d_out, int out_size, void* d_ws, size_t ws_size,
                              hipStream_t stream) {
    const float* x    = (const float*)d_in[0];
    const float* pos  = (const float*)d_in[1];
    const float* Wq   = (const float*)d_in[2];
    const float* Wk   = (const float*)d_in[3];
    const float* pw1  = (const float*)d_in[4];
    const float* pb1  = (const float*)d_in[5];
    const float* pw2  = (const float*)d_in[6];
    const float* pb2  = (const float*)d_in[7];
    const float* hw   = (const float*)d_in[8];
    // d_in[9] = head_b: cancels in softmax over t -> unused
    const float* gate = (const float*)d_in[10];
    const float* vemb = (const float*)d_in[11];
    const float* ow   = (const float*)d_in[12];
    const float* ob   = (const float*)d_in[13];
    float* out = (float*)d_out;

    const size_t NBS = (size_t)MROWS * DD;      // 4194304 elements
    u16* Qh  = (u16*)d_ws;
    u16* Ql  = Qh + NBS;
    u16* Kh  = Ql + NBS;
    u16* Vh  = Kh + NBS;
    u16* Oh  = Vh + NBS;
    u16* Ol  = Oh + NBS;
    u16* Xh  = Ol + NBS;
    u16* Xl  = Xh + NBS;
    u16* WHp = Xl + NBS;                        // 262144 u16
    float* Eb  = (float*)(WHp + 262144);        // 131072 floats [B,H,S]
    float* PVn = Eb + 131072;                   // 16384 floats [B*H][32]

    hipLaunchKernelGGL(wconv, dim3(256), dim3(256), 0, stream,
                       Wq, Wk, vemb, ow, WHp);
    hipLaunchKernelGGL(xsplit, dim3(MROWS*DD/2048), dim3(256), 0, stream,
                       x, Xh, Xl);
    hipLaunchKernelGGL(pos_kernel, dim3(MROWS / 256), dim3(256), 0, stream,
                       pos, pw1, pb1, pw2, pb2, hw, Eb);
    hipLaunchKernelGGL((gemm_mfma<1>), dim3(6, MROWS/128), dim3(256), 0, stream,
                       Xh, Xl, WHp, nullptr, nullptr, Qh, Ql, Kh, Vh, 0);
    hipLaunchKernelGGL(posv, dim3(BB*HH), dim3(256), 0, stream,
                       Eb, Vh, PVn);
    hipLaunchKernelGGL(attn_kernel, dim3(BB*HH*2), dim3(256), 0, stream,
                       Qh, Ql, Kh, Vh, PVn, gate, Oh, Ol);
    hipLaunchKernelGGL((gemm_mfma<0>), dim3(2, MROWS/128), dim3(256), 0, stream,
                       Oh, Ol, WHp, ob, out, nullptr, nullptr, nullptr, nullptr, 768);
}

// Round 10
// 160.060 us; speedup vs baseline: 1.1034x; 1.1034x over previous
//
#include <hip/hip_runtime.h>
#include <math.h>

// Problem constants (B,S,D,H,PD = 64,256,256,8,8)
#define BB 64
#define SS 256
#define DD 256
#define HH 8
#define HDIM 32
#define MROWS (BB*SS)   // 16384

typedef unsigned short u16;
typedef unsigned int u32;
typedef _Float16 f16;
typedef __attribute__((ext_vector_type(8))) _Float16 half8;  // 4 VGPR MFMA frag
typedef __attribute__((ext_vector_type(16))) float f32x16;   // 32x32 MFMA acc

union U4H8 { uint4 u; half8 h; u16 s[8]; };

__device__ __forceinline__ u16 f16b(float a) {               // RNE f32->f16
    f16 h = (f16)a; return __builtin_bit_cast(u16, h);
}
__device__ __forceinline__ u32 pk_rne(float a, float b) {
    return (u32)f16b(a) | ((u32)f16b(b) << 16);
}
// RTZ-split: hw = pkrtz(a,b); lw captures residual exactly (err ~2^-21)
__device__ __forceinline__ void pksplit2(float a, float b, u32& hw, u32& lw) {
    auto h = __builtin_amdgcn_cvt_pkrtz(a, b);
    hw = __builtin_bit_cast(u32, h);
    auto l = __builtin_amdgcn_cvt_pkrtz(a - (float)h[0], b - (float)h[1]);
    lw = __builtin_bit_cast(u32, l);
}
__device__ __forceinline__ void split8f(const float* e, uint4& h4, uint4& l4) {
    pksplit2(e[0], e[1], h4.x, l4.x);
    pksplit2(e[2], e[3], h4.y, l4.y);
    pksplit2(e[4], e[5], h4.z, l4.z);
    pksplit2(e[6], e[7], h4.w, l4.w);
}
__device__ __forceinline__ f32x16 mfma16f(half8 a, half8 b, f32x16 c) {
    return __builtin_amdgcn_mfma_f32_32x32x16_f16(a, b, c, 0, 0, 0);
}

// ---------------------------------------------------------------------------
// prep: block-range fused preprocessing.
//  blocks [0,256): weight convert — stack [Wq;Wk;Wv;Wo] -> single fp16 WH.
//  blocks [256,320): pos-MLP -> E[b,h,s] = p(b,s)·head_w[h].
//  (head_b and the e_s term cancel in softmax over t -> pos_attn =
//   softmax_t(-e_t), s-independent.)
// ---------------------------------------------------------------------------
__global__ __launch_bounds__(256)
void prep(const float* __restrict__ Wq, const float* __restrict__ Wk,
          const float* __restrict__ Wv, const float* __restrict__ Wo,
          u16* __restrict__ WH,
          const float* __restrict__ pos, const float* __restrict__ w1,
          const float* __restrict__ b1, const float* __restrict__ w2,
          const float* __restrict__ b2, const float* __restrict__ hw,
          float* __restrict__ E) {
    __shared__ float sw1[64], sb1[8], sw2[256], sb2[32], shw[256];
    const int tid = threadIdx.x;

    if (blockIdx.x < 256) {                     // ---- weight convert ----
        const int bx = blockIdx.x;
        const int sel = bx >> 6;
        const float* src = (sel == 0) ? Wq : (sel == 1) ? Wk
                         : (sel == 2) ? Wv : Wo;
        const int i = (bx & 63) * 1024 + tid * 4;
        float4 v = *reinterpret_cast<const float4*>(src + i);
        *reinterpret_cast<uint2*>(WH + (size_t)sel * 65536 + i) =
            make_uint2(pk_rne(v.x, v.y), pk_rne(v.z, v.w));
        return;
    }

    // ---- pos-MLP ----
    if (tid < 64)  sw1[tid] = w1[tid];
    if (tid < 8)   sb1[tid] = b1[tid];
    sw2[tid] = w2[tid];
    if (tid < 32)  sb2[tid] = b2[tid];
    shw[tid] = hw[tid];
    __syncthreads();

    const int row = (blockIdx.x - 256) * 256 + tid;   // 0..16383
    float pv[8];
    float4 p0 = *reinterpret_cast<const float4*>(pos + (size_t)row * 8);
    float4 p1 = *reinterpret_cast<const float4*>(pos + (size_t)row * 8 + 4);
    pv[0]=p0.x; pv[1]=p0.y; pv[2]=p0.z; pv[3]=p0.w;
    pv[4]=p1.x; pv[5]=p1.y; pv[6]=p1.z; pv[7]=p1.w;

    float h1[8];
    #pragma unroll
    for (int j = 0; j < 8; j++) {
        float a = sb1[j];
        #pragma unroll
        for (int i = 0; i < 8; i++) a = fmaf(pv[i], sw1[j*8+i], a);
        h1[j] = fmaxf(a, 0.f);
    }
    float p[32];
    #pragma unroll
    for (int c = 0; c < 32; c++) {
        float a = sb2[c];
        #pragma unroll
        for (int j = 0; j < 8; j++) a = fmaf(h1[j], sw2[c*8+j], a);
        p[c] = a;
    }
    const int b = row >> 8, s = row & 255;
    #pragma unroll
    for (int h = 0; h < 8; h++) {
        float e = 0.f;
        #pragma unroll
        for (int c = 0; c < 32; c++) e = fmaf(p[c], shw[h*32+c], e);
        E[((size_t)(b*8 + h) << 8) + s] = e;
    }
}

// ---------------------------------------------------------------------------
// fp16 MFMA GEMM: C[M,N] = A[M,256] @ W[N,256]^T (+bias), via Ah*W + Al*W
// (A split exact via pkrtz; W single fp16).  BM=128, BN=128, BK=32,
// 4 waves x 64x64.  A reg-staged fp32->split->LDS (stride-40 u16 rows).
// W frags from global (L2-resident).  QKV=true: bx in [0,6): sel=bx>>1.
// ---------------------------------------------------------------------------
template<bool QKV>
__global__ __launch_bounds__(256, 3)
void gemm_mfma(const float* __restrict__ A, const u16* __restrict__ WH,
               const float* __restrict__ bias,
               float* __restrict__ C0, float* __restrict__ C1,
               float* __restrict__ C2, int wbase) {
    __shared__ u16 Ah[128*40], Al[128*40];

    const int tid = threadIdx.x;
    const int lane = tid & 63, wv = tid >> 6;
    const int wm = wv >> 1, wn = wv & 1;
    const int hh = lane >> 5, ln = lane & 31;
    const int bx = blockIdx.x, m0 = blockIdx.y * 128;

    float* C; int n0, nstack0;
    if (QKV) {
        const int sel = bx >> 1;
        C = (sel == 0) ? C0 : (sel == 1) ? C1 : C2;
        n0 = (bx & 1) * 128;
        nstack0 = bx * 128;
    } else {
        C = C0; n0 = bx * 128; nstack0 = wbase + bx * 128;
    }

    f32x16 acc[2][2];
    #pragma unroll
    for (int i = 0; i < 2; i++)
        #pragma unroll
        for (int j = 0; j < 2; j++)
            #pragma unroll
            for (int r = 0; r < 16; r++) acc[i][j][r] = 0.f;

    const int g0 = tid, g1 = 256 + tid;
    const int r0 = g0 >> 2, c80 = g0 & 3;
    const int r1 = g1 >> 2, c81 = g1 & 3;
    const float* pA0 = A + (size_t)(m0 + r0) * 256 + c80 * 8;
    const float* pA1 = A + (size_t)(m0 + r1) * 256 + c81 * 8;

    const u16* WHrow = WH + (size_t)(nstack0 + wn*64 + ln) * 256;

    float4 fa0 = *reinterpret_cast<const float4*>(pA0);
    float4 fb0 = *reinterpret_cast<const float4*>(pA0 + 4);
    float4 fa1 = *reinterpret_cast<const float4*>(pA1);
    float4 fb1 = *reinterpret_cast<const float4*>(pA1 + 4);

    #pragma unroll
    for (int s = 0; s < 8; s++) {
        const int kb = s * 32;
        {
            uint4 h4, l4;
            float e0[8] = {fa0.x,fa0.y,fa0.z,fa0.w,fb0.x,fb0.y,fb0.z,fb0.w};
            split8f(e0, h4, l4);
            *reinterpret_cast<uint4*>(&Ah[r0*40 + c80*8]) = h4;
            *reinterpret_cast<uint4*>(&Al[r0*40 + c80*8]) = l4;
            float e1[8] = {fa1.x,fa1.y,fa1.z,fa1.w,fb1.x,fb1.y,fb1.z,fb1.w};
            split8f(e1, h4, l4);
            *reinterpret_cast<uint4*>(&Ah[r1*40 + c81*8]) = h4;
            *reinterpret_cast<uint4*>(&Al[r1*40 + c81*8]) = l4;
        }
        __syncthreads();
        if (s < 7) {
            fa0 = *reinterpret_cast<const float4*>(pA0 + kb + 32);
            fb0 = *reinterpret_cast<const float4*>(pA0 + kb + 36);
            fa1 = *reinterpret_cast<const float4*>(pA1 + kb + 32);
            fb1 = *reinterpret_cast<const float4*>(pA1 + kb + 36);
        }

        U4H8 wf[2][2];                          // [tn][ks]
        #pragma unroll
        for (int tn = 0; tn < 2; tn++)
            #pragma unroll
            for (int ks = 0; ks < 2; ks++)
                wf[tn][ks].u = *reinterpret_cast<const uint4*>(
                    WHrow + (size_t)tn*32*256 + kb + ks*16 + hh*8);
        U4H8 afh[2][2], afl[2][2];              // [tm][ks]
        #pragma unroll
        for (int tm = 0; tm < 2; tm++)
            #pragma unroll
            for (int ks = 0; ks < 2; ks++) {
                const int el = (wm*64 + tm*32 + ln)*40 + ks*16 + hh*8;
                afh[tm][ks].u = *reinterpret_cast<const uint4*>(&Ah[el]);
                afl[tm][ks].u = *reinterpret_cast<const uint4*>(&Al[el]);
            }
        __builtin_amdgcn_s_setprio(1);
        #pragma unroll
        for (int tm = 0; tm < 2; tm++)
            #pragma unroll
            for (int tn = 0; tn < 2; tn++)
                #pragma unroll
                for (int ks = 0; ks < 2; ks++) {
                    acc[tm][tn] = mfma16f(afh[tm][ks].h, wf[tn][ks].h, acc[tm][tn]);
                    acc[tm][tn] = mfma16f(afl[tm][ks].h, wf[tn][ks].h, acc[tm][tn]);
                }
        __builtin_amdgcn_s_setprio(0);
        __syncthreads();
    }

    #pragma unroll
    for (int tm = 0; tm < 2; tm++)
        #pragma unroll
        for (int tn = 0; tn < 2; tn++) {
            float bv = 0.f;
            if (!QKV) bv = bias[n0 + wn*64 + tn*32 + ln];
            #pragma unroll
            for (int r = 0; r < 16; r++) {
                const int mm = m0 + wm*64 + tm*32 + (r&3) + 8*(r>>2) + 4*hh;
                C[(size_t)mm*256 + n0 + wn*64 + tn*32 + ln] = acc[tm][tn][r] + bv;
            }
        }
}

// ---------------------------------------------------------------------------
// fp16 MFMA attention.  Grid 1024: block = (b, h, half of S) -> exactly
// 4 blocks/CU (LDS 39.6KB x4 = 158KB).  4 waves, one 32-row q-tile each.
// K,V single fp16 (RNE); Q,P split hi+lo fp16 (pkrtz).  pos branch: pv
// vector computed in-block (s-independent), blended in epilogue.
// S^T = mfma(K,Q); P frag from C-regs via pack + shfl_xor(32) + select;
// O^T = mfma(Vt, P).
// ---------------------------------------------------------------------------
__global__ __launch_bounds__(256, 4)
void attn_kernel(const float* __restrict__ Q, const float* __restrict__ Kb,
                 const float* __restrict__ Vb, const float* __restrict__ E,
                 const float* __restrict__ gate, float* __restrict__ O) {
    __shared__ u16 Ks[256*40];       // f16 bits, rows of 32, pad to 40
    __shared__ u16 Vt[32*264];       // [d][t] rows pad to 264
    __shared__ float ws[256];
    __shared__ float red[4];
    __shared__ float pvp[8][33];
    __shared__ float pvs[32];

    const int tid = threadIdx.x;
    const int bid = blockIdx.x;
    const int bh = bid >> 1, hb = bid & 1;
    const int b = bh >> 3, h = bh & 7;
    const size_t base = (size_t)b * SS * DD + (size_t)h * HDIM;
    const float SCALE = 0.17677669529663687f;    // 1/sqrt(32)

    // ---- stage K, V^T (single fp16); one (b,h)-row per thread -------------
    {
        const int t = tid;
        const float* kr = Kb + base + (size_t)t * DD;
        const float* vr = Vb + base + (size_t)t * DD;
        float kx[32], vx[32];
        #pragma unroll
        for (int i = 0; i < 8; i++) {
            float4 kv = *reinterpret_cast<const float4*>(kr + i*4);
            float4 vv = *reinterpret_cast<const float4*>(vr + i*4);
            kx[i*4+0]=kv.x; kx[i*4+1]=kv.y; kx[i*4+2]=kv.z; kx[i*4+3]=kv.w;
            vx[i*4+0]=vv.x; vx[i*4+1]=vv.y; vx[i*4+2]=vv.z; vx[i*4+3]=vv.w;
        }
        #pragma unroll
        for (int c = 0; c < 4; c++) {
            uint4 w;
            w.x = pk_rne(kx[c*8+0], kx[c*8+1]);
            w.y = pk_rne(kx[c*8+2], kx[c*8+3]);
            w.z = pk_rne(kx[c*8+4], kx[c*8+5]);
            w.w = pk_rne(kx[c*8+6], kx[c*8+7]);
            *reinterpret_cast<uint4*>(&Ks[t*40 + c*8]) = w;
        }
        #pragma unroll
        for (int d = 0; d < 32; d++) Vt[d*264 + t] = f16b(vx[d]);

        float w = __expf(-E[((size_t)bh << 8) + t]);
        ws[t] = w;
        float v = w;
        #pragma unroll
        for (int off = 32; off > 0; off >>= 1) v += __shfl_down(v, off);
        if ((tid & 63) == 0) red[tid >> 6] = v;
    }
    __syncthreads();
    const float psum = red[0] + red[1] + red[2] + red[3];

    // ---- pv[d] = sum_t w_t V[t][d] ---------------------------------------
    {
        int d = tid & 31, ch = tid >> 5;
        float acc = 0.f;
        #pragma unroll
        for (int tb = 0; tb < 4; tb++) {
            U4H8 hv;
            hv.u = *reinterpret_cast<const uint4*>(&Vt[d*264 + ch*32 + tb*8]);
            #pragma unroll
            for (int j = 0; j < 8; j++)
                acc = fmaf(ws[ch*32 + tb*8 + j], (float)hv.h[j], acc);
        }
        pvp[ch][d] = acc;
    }
    __syncthreads();
    if (tid < 32) {
        float s = 0.f;
        #pragma unroll
        for (int i = 0; i < 8; i++) s += pvp[i][tid];
        pvs[tid] = s;
    }
    __syncthreads();

    // ---- main: wave wv handles q-tile q0 = hb*128 + wv*32 -----------------
    const int lane = tid & 63, wv = tid >> 6;
    const int hh2 = lane >> 5, lq = lane & 31;
    const float g = 1.f / (1.f + __expf(-gate[h]));
    const float c2 = g / psum;
    const int q0 = hb*128 + wv*32;

    // Q fragments: hi+lo fp16 split (exact)
    U4H8 qh[2], ql[2];
    const float* qrow = Q + base + (size_t)(q0 + lq) * DD;
    #pragma unroll
    for (int ks = 0; ks < 2; ks++) {
        float4 a = *reinterpret_cast<const float4*>(qrow + ks*16 + hh2*8);
        float4 c = *reinterpret_cast<const float4*>(qrow + ks*16 + hh2*8 + 4);
        float e[8] = {a.x,a.y,a.z,a.w,c.x,c.y,c.z,c.w};
        split8f(e, qh[ks].u, ql[ks].u);
    }

    f32x16 acco;
    #pragma unroll
    for (int r = 0; r < 16; r++) acco[r] = 0.f;
    float rowsum = 0.f;

    #pragma unroll
    for (int tt = 0; tt < 8; tt++) {
        // S^T tile: K single x (Qh + Ql)
        f32x16 accs;
        #pragma unroll
        for (int r = 0; r < 16; r++) accs[r] = 0.f;
        const int trow = tt*32 + lq;
        __builtin_amdgcn_s_setprio(1);
        #pragma unroll
        for (int ks = 0; ks < 2; ks++) {
            U4H8 kf;
            kf.u = *reinterpret_cast<const uint4*>(&Ks[trow*40 + ks*16 + hh2*8]);
            accs = mfma16f(kf.h, qh[ks].h, accs);
            accs = mfma16f(kf.h, ql[ks].h, accs);
        }
        __builtin_amdgcn_s_setprio(0);
        // P = exp(S*scale): split hi+lo fp16, packed
        u32 PH[8], PL[8];
        #pragma unroll
        for (int j = 0; j < 8; j++) {
            float p0 = __expf(accs[2*j]   * SCALE);
            float p1 = __expf(accs[2*j+1] * SCALE);
            rowsum += p0 + p1;
            pksplit2(p0, p1, PH[j], PL[j]);
        }
        // PV: B-frag from C-regs via shfl_xor(32) half-swap + select
        #pragma unroll
        for (int ks = 0; ks < 2; ks++) {
            u32 HA0 = PH[ks*4+0], HA1 = PH[ks*4+1];
            u32 HB0 = PH[ks*4+2], HB1 = PH[ks*4+3];
            u32 LA0 = PL[ks*4+0], LA1 = PL[ks*4+1];
            u32 LB0 = PL[ks*4+2], LB1 = PL[ks*4+3];
            u32 XA0 = (u32)__shfl_xor((int)HA0, 32);
            u32 XA1 = (u32)__shfl_xor((int)HA1, 32);
            u32 XB0 = (u32)__shfl_xor((int)HB0, 32);
            u32 XB1 = (u32)__shfl_xor((int)HB1, 32);
            u32 YA0 = (u32)__shfl_xor((int)LA0, 32);
            u32 YA1 = (u32)__shfl_xor((int)LA1, 32);
            u32 YB0 = (u32)__shfl_xor((int)LB0, 32);
            u32 YB1 = (u32)__shfl_xor((int)LB1, 32);
            U4H8 bhf, blf, vf;
            bhf.u = make_uint4(hh2 ? XB0 : HA0, hh2 ? XB1 : HA1,
                               hh2 ? HB0 : XA0, hh2 ? HB1 : XA1);
            blf.u = make_uint4(hh2 ? YB0 : LA0, hh2 ? YB1 : LA1,
                               hh2 ? LB0 : YA0, hh2 ? LB1 : YA1);
            vf.u = *reinterpret_cast<const uint4*>(
                &Vt[lq*264 + tt*32 + ks*16 + hh2*8]);
            __builtin_amdgcn_s_setprio(1);
            acco = mfma16f(vf.h, bhf.h, acco);
            acco = mfma16f(vf.h, blf.h, acco);
            __builtin_amdgcn_s_setprio(0);
        }
    }

    rowsum += __shfl_xor(rowsum, 32);
    const float c1 = (1.f - g) / rowsum;
    float* orow = O + base + (size_t)(q0 + lq) * DD;
    #pragma unroll
    for (int r = 0; r < 16; r++) {
        int d = (r & 3) + 8*(r >> 2) + 4*hh2;
        orow[d] = c1 * acco[r] + c2 * pvs[d];
    }
}

// ---------------------------------------------------------------------------
extern "C" void kernel_launch(void* const* d_in, const int* in_sizes, int n_in,
                              void* d_out, int out_size, void* d_ws, size_t ws_size,
                              hipStream_t stream) {
    const float* x    = (const float*)d_in[0];
    const float* pos  = (const float*)d_in[1];
    const float* Wq   = (const float*)d_in[2];
    const float* Wk   = (const float*)d_in[3];
    const float* pw1  = (const float*)d_in[4];
    const float* pb1  = (const float*)d_in[5];
    const float* pw2  = (const float*)d_in[6];
    const float* pb2  = (const float*)d_in[7];
    const float* hw   = (const float*)d_in[8];
    // d_in[9] = head_b: cancels in softmax over t -> unused
    const float* gate = (const float*)d_in[10];
    const float* vemb = (const float*)d_in[11];
    const float* ow   = (const float*)d_in[12];
    const float* ob   = (const float*)d_in[13];
    float* out = (float*)d_out;

    const size_t NBS = (size_t)MROWS * DD;      // 4194304
    float* Qb   = (float*)d_ws;
    float* Kbuf = Qb + NBS;
    float* Vbuf = Kbuf + NBS;
    float* Ob   = Vbuf + NBS;
    float* Eb   = Ob + NBS;                     // 131072 floats
    u16*  WHp  = (u16*)(Eb + 131072);           // stacked [1024][256] f16

    hipLaunchKernelGGL(prep, dim3(256 + MROWS/256), dim3(256), 0, stream,
                       Wq, Wk, vemb, ow, WHp,
                       pos, pw1, pb1, pw2, pb2, hw, Eb);
    hipLaunchKernelGGL((gemm_mfma<true>), dim3(6, MROWS/128), dim3(256), 0, stream,
                       x, WHp, nullptr, Qb, Kbuf, Vbuf, 0);
    hipLaunchKernelGGL(attn_kernel, dim3(BB*HH*2), dim3(256), 0, stream,
                       Qb, Kbuf, Vbuf, Eb, gate, Ob);
    hipLaunchKernelGGL((gemm_mfma<false>), dim3(2, MROWS/128), dim3(256), 0, stream,
                       Ob, WHp, ob, out, out, out, 768);
}

// Round 11
// 158.982 us; speedup vs baseline: 1.1109x; 1.0068x over previous
//
#include <hip/hip_runtime.h>
#include <math.h>

// Problem constants (B,S,D,H,PD = 64,256,256,8,8)
#define BB 64
#define SS 256
#define DD 256
#define HH 8
#define HDIM 32
#define MROWS (BB*SS)   // 16384

typedef unsigned short u16;
typedef unsigned int u32;
typedef _Float16 f16;
typedef __attribute__((ext_vector_type(8))) _Float16 half8;  // 4 VGPR MFMA frag
typedef __attribute__((ext_vector_type(16))) float f32x16;   // 32x32 MFMA acc

union U4H8 { uint4 u; half8 h; u16 s[8]; };

__device__ __forceinline__ u16 f16b(float a) {               // RNE f32->f16
    f16 h = (f16)a; return __builtin_bit_cast(u16, h);
}
__device__ __forceinline__ u32 pk_rne(float a, float b) {
    return (u32)f16b(a) | ((u32)f16b(b) << 16);
}
// RTZ-split: hw = pkrtz(a,b); lw captures residual exactly (err ~2^-21)
__device__ __forceinline__ void pksplit2(float a, float b, u32& hw, u32& lw) {
    auto h = __builtin_amdgcn_cvt_pkrtz(a, b);
    hw = __builtin_bit_cast(u32, h);
    auto l = __builtin_amdgcn_cvt_pkrtz(a - (float)h[0], b - (float)h[1]);
    lw = __builtin_bit_cast(u32, l);
}
__device__ __forceinline__ void split8f(const float* e, uint4& h4, uint4& l4) {
    pksplit2(e[0], e[1], h4.x, l4.x);
    pksplit2(e[2], e[3], h4.y, l4.y);
    pksplit2(e[4], e[5], h4.z, l4.z);
    pksplit2(e[6], e[7], h4.w, l4.w);
}
__device__ __forceinline__ f32x16 mfma16f(half8 a, half8 b, f32x16 c) {
    return __builtin_amdgcn_mfma_f32_32x32x16_f16(a, b, c, 0, 0, 0);
}

// ---------------------------------------------------------------------------
// prep: block-range fused preprocessing.
//  blocks [0,256): weight convert — stack [Wq;Wk;Wv;Wo] -> single fp16 WH.
//  blocks [256,320): pos-MLP -> E[b,h,s] = p(b,s)·head_w[h].
//  (head_b and the e_s term cancel in softmax over t -> pos_attn =
//   softmax_t(-e_t), s-independent.)
// ---------------------------------------------------------------------------
__global__ __launch_bounds__(256)
void prep(const float* __restrict__ Wq, const float* __restrict__ Wk,
          const float* __restrict__ Wv, const float* __restrict__ Wo,
          u16* __restrict__ WH,
          const float* __restrict__ pos, const float* __restrict__ w1,
          const float* __restrict__ b1, const float* __restrict__ w2,
          const float* __restrict__ b2, const float* __restrict__ hw,
          float* __restrict__ E) {
    __shared__ float sw1[64], sb1[8], sw2[256], sb2[32], shw[256];
    const int tid = threadIdx.x;

    if (blockIdx.x < 256) {                     // ---- weight convert ----
        const int bx = blockIdx.x;
        const int sel = bx >> 6;
        const float* src = (sel == 0) ? Wq : (sel == 1) ? Wk
                         : (sel == 2) ? Wv : Wo;
        const int i = (bx & 63) * 1024 + tid * 4;
        float4 v = *reinterpret_cast<const float4*>(src + i);
        *reinterpret_cast<uint2*>(WH + (size_t)sel * 65536 + i) =
            make_uint2(pk_rne(v.x, v.y), pk_rne(v.z, v.w));
        return;
    }

    // ---- pos-MLP ----
    if (tid < 64)  sw1[tid] = w1[tid];
    if (tid < 8)   sb1[tid] = b1[tid];
    sw2[tid] = w2[tid];
    if (tid < 32)  sb2[tid] = b2[tid];
    shw[tid] = hw[tid];
    __syncthreads();

    const int row = (blockIdx.x - 256) * 256 + tid;   // 0..16383
    float pv[8];
    float4 p0 = *reinterpret_cast<const float4*>(pos + (size_t)row * 8);
    float4 p1 = *reinterpret_cast<const float4*>(pos + (size_t)row * 8 + 4);
    pv[0]=p0.x; pv[1]=p0.y; pv[2]=p0.z; pv[3]=p0.w;
    pv[4]=p1.x; pv[5]=p1.y; pv[6]=p1.z; pv[7]=p1.w;

    float h1[8];
    #pragma unroll
    for (int j = 0; j < 8; j++) {
        float a = sb1[j];
        #pragma unroll
        for (int i = 0; i < 8; i++) a = fmaf(pv[i], sw1[j*8+i], a);
        h1[j] = fmaxf(a, 0.f);
    }
    float p[32];
    #pragma unroll
    for (int c = 0; c < 32; c++) {
        float a = sb2[c];
        #pragma unroll
        for (int j = 0; j < 8; j++) a = fmaf(h1[j], sw2[c*8+j], a);
        p[c] = a;
    }
    const int b = row >> 8, s = row & 255;
    #pragma unroll
    for (int h = 0; h < 8; h++) {
        float e = 0.f;
        #pragma unroll
        for (int c = 0; c < 32; c++) e = fmaf(p[c], shw[h*32+c], e);
        E[((size_t)(b*8 + h) << 8) + s] = e;
    }
}

// ---------------------------------------------------------------------------
// fp16 MFMA GEMM: C[M,N] = A[M,256] @ W[N,256]^T (+bias), via Ah*W + Al*W
// (A split exact via pkrtz; W single fp16).  BM=128, BN=128, BK=32,
// 4 waves x 64x64.  A reg-staged fp32->split->LDS, **double-buffered**:
// one barrier per K-step; split+write of step s+1 targets buf cur^1 while
// other waves read buf cur (disjoint -> race-free; next barrier publishes).
// W frags from global (L2-resident).  QKV=true: bx in [0,6): sel=bx>>1.
// ---------------------------------------------------------------------------
template<bool QKV>
__global__ __launch_bounds__(256, 3)
void gemm_mfma(const float* __restrict__ A, const u16* __restrict__ WH,
               const float* __restrict__ bias,
               float* __restrict__ C0, float* __restrict__ C1,
               float* __restrict__ C2, int wbase) {
    __shared__ u16 Ah[2][128*40], Al[2][128*40];

    const int tid = threadIdx.x;
    const int lane = tid & 63, wv = tid >> 6;
    const int wm = wv >> 1, wn = wv & 1;
    const int hh = lane >> 5, ln = lane & 31;
    const int bx = blockIdx.x, m0 = blockIdx.y * 128;

    float* C; int n0, nstack0;
    if (QKV) {
        const int sel = bx >> 1;
        C = (sel == 0) ? C0 : (sel == 1) ? C1 : C2;
        n0 = (bx & 1) * 128;
        nstack0 = bx * 128;
    } else {
        C = C0; n0 = bx * 128; nstack0 = wbase + bx * 128;
    }

    f32x16 acc[2][2];
    #pragma unroll
    for (int i = 0; i < 2; i++)
        #pragma unroll
        for (int j = 0; j < 2; j++)
            #pragma unroll
            for (int r = 0; r < 16; r++) acc[i][j][r] = 0.f;

    const int g0 = tid, g1 = 256 + tid;
    const int r0 = g0 >> 2, c80 = g0 & 3;
    const int r1 = g1 >> 2, c81 = g1 & 3;
    const float* pA0 = A + (size_t)(m0 + r0) * 256 + c80 * 8;
    const float* pA1 = A + (size_t)(m0 + r1) * 256 + c81 * 8;

    const u16* WHrow = WH + (size_t)(nstack0 + wn*64 + ln) * 256;

    // ---- stage s=0 into buf 0 --------------------------------------------
    {
        float4 fa0 = *reinterpret_cast<const float4*>(pA0);
        float4 fb0 = *reinterpret_cast<const float4*>(pA0 + 4);
        float4 fa1 = *reinterpret_cast<const float4*>(pA1);
        float4 fb1 = *reinterpret_cast<const float4*>(pA1 + 4);
        uint4 h4, l4;
        float e0[8] = {fa0.x,fa0.y,fa0.z,fa0.w,fb0.x,fb0.y,fb0.z,fb0.w};
        split8f(e0, h4, l4);
        *reinterpret_cast<uint4*>(&Ah[0][r0*40 + c80*8]) = h4;
        *reinterpret_cast<uint4*>(&Al[0][r0*40 + c80*8]) = l4;
        float e1[8] = {fa1.x,fa1.y,fa1.z,fa1.w,fb1.x,fb1.y,fb1.z,fb1.w};
        split8f(e1, h4, l4);
        *reinterpret_cast<uint4*>(&Ah[0][r1*40 + c81*8]) = h4;
        *reinterpret_cast<uint4*>(&Al[0][r1*40 + c81*8]) = l4;
    }

    #pragma unroll
    for (int s = 0; s < 8; s++) {
        const int cur = s & 1;
        const int kb = s * 32;
        __syncthreads();                        // buf[cur] published

        // issue next-step A global loads (latency covered by MFMA below)
        float4 fa0, fb0, fa1, fb1;
        if (s < 7) {
            fa0 = *reinterpret_cast<const float4*>(pA0 + kb + 32);
            fb0 = *reinterpret_cast<const float4*>(pA0 + kb + 36);
            fa1 = *reinterpret_cast<const float4*>(pA1 + kb + 32);
            fb1 = *reinterpret_cast<const float4*>(pA1 + kb + 36);
        }

        U4H8 wf[2][2];                          // [tn][ks]
        #pragma unroll
        for (int tn = 0; tn < 2; tn++)
            #pragma unroll
            for (int ks = 0; ks < 2; ks++)
                wf[tn][ks].u = *reinterpret_cast<const uint4*>(
                    WHrow + (size_t)tn*32*256 + kb + ks*16 + hh*8);
        U4H8 afh[2][2], afl[2][2];              // [tm][ks]
        #pragma unroll
        for (int tm = 0; tm < 2; tm++)
            #pragma unroll
            for (int ks = 0; ks < 2; ks++) {
                const int el = (wm*64 + tm*32 + ln)*40 + ks*16 + hh*8;
                afh[tm][ks].u = *reinterpret_cast<const uint4*>(&Ah[cur][el]);
                afl[tm][ks].u = *reinterpret_cast<const uint4*>(&Al[cur][el]);
            }
        __builtin_amdgcn_s_setprio(1);
        #pragma unroll
        for (int tm = 0; tm < 2; tm++)
            #pragma unroll
            for (int tn = 0; tn < 2; tn++)
                #pragma unroll
                for (int ks = 0; ks < 2; ks++) {
                    acc[tm][tn] = mfma16f(afh[tm][ks].h, wf[tn][ks].h, acc[tm][tn]);
                    acc[tm][tn] = mfma16f(afl[tm][ks].h, wf[tn][ks].h, acc[tm][tn]);
                }
        __builtin_amdgcn_s_setprio(0);

        // split + write NEXT buffer (disjoint from buf[cur] readers)
        if (s < 7) {
            uint4 h4, l4;
            float e0[8] = {fa0.x,fa0.y,fa0.z,fa0.w,fb0.x,fb0.y,fb0.z,fb0.w};
            split8f(e0, h4, l4);
            *reinterpret_cast<uint4*>(&Ah[cur^1][r0*40 + c80*8]) = h4;
            *reinterpret_cast<uint4*>(&Al[cur^1][r0*40 + c80*8]) = l4;
            float e1[8] = {fa1.x,fa1.y,fa1.z,fa1.w,fb1.x,fb1.y,fb1.z,fb1.w};
            split8f(e1, h4, l4);
            *reinterpret_cast<uint4*>(&Ah[cur^1][r1*40 + c81*8]) = h4;
            *reinterpret_cast<uint4*>(&Al[cur^1][r1*40 + c81*8]) = l4;
        }
    }

    #pragma unroll
    for (int tm = 0; tm < 2; tm++)
        #pragma unroll
        for (int tn = 0; tn < 2; tn++) {
            float bv = 0.f;
            if (!QKV) bv = bias[n0 + wn*64 + tn*32 + ln];
            #pragma unroll
            for (int r = 0; r < 16; r++) {
                const int mm = m0 + wm*64 + tm*32 + (r&3) + 8*(r>>2) + 4*hh;
                C[(size_t)mm*256 + n0 + wn*64 + tn*32 + ln] = acc[tm][tn][r] + bv;
            }
        }
}

// ---------------------------------------------------------------------------
// fp16 MFMA attention.  Grid 1024: block = (b, h, half of S) -> 4 blocks/CU
// (LDS 39.6KB x4 = 158KB).  4 waves, one 32-row q-tile each.
// K,V single fp16 (RNE); Q,P split hi+lo fp16 (pkrtz).  pos branch: pv
// vector computed in-block (s-independent), blended in epilogue.
// S^T = mfma(K,Q); P frag from C-regs via pack + shfl_xor(32) + select;
// O^T = mfma(Vt, P).   (byte-identical to the measured 160 µs version)
// ---------------------------------------------------------------------------
__global__ __launch_bounds__(256, 4)
void attn_kernel(const float* __restrict__ Q, const float* __restrict__ Kb,
                 const float* __restrict__ Vb, const float* __restrict__ E,
                 const float* __restrict__ gate, float* __restrict__ O) {
    __shared__ u16 Ks[256*40];       // f16 bits, rows of 32, pad to 40
    __shared__ u16 Vt[32*264];       // [d][t] rows pad to 264
    __shared__ float ws[256];
    __shared__ float red[4];
    __shared__ float pvp[8][33];
    __shared__ float pvs[32];

    const int tid = threadIdx.x;
    const int bid = blockIdx.x;
    const int bh = bid >> 1, hb = bid & 1;
    const int b = bh >> 3, h = bh & 7;
    const size_t base = (size_t)b * SS * DD + (size_t)h * HDIM;
    const float SCALE = 0.17677669529663687f;    // 1/sqrt(32)

    // ---- stage K, V^T (single fp16); one (b,h)-row per thread -------------
    {
        const int t = tid;
        const float* kr = Kb + base + (size_t)t * DD;
        const float* vr = Vb + base + (size_t)t * DD;
        float kx[32], vx[32];
        #pragma unroll
        for (int i = 0; i < 8; i++) {
            float4 kv = *reinterpret_cast<const float4*>(kr + i*4);
            float4 vv = *reinterpret_cast<const float4*>(vr + i*4);
            kx[i*4+0]=kv.x; kx[i*4+1]=kv.y; kx[i*4+2]=kv.z; kx[i*4+3]=kv.w;
            vx[i*4+0]=vv.x; vx[i*4+1]=vv.y; vx[i*4+2]=vv.z; vx[i*4+3]=vv.w;
        }
        #pragma unroll
        for (int c = 0; c < 4; c++) {
            uint4 w;
            w.x = pk_rne(kx[c*8+0], kx[c*8+1]);
            w.y = pk_rne(kx[c*8+2], kx[c*8+3]);
            w.z = pk_rne(kx[c*8+4], kx[c*8+5]);
            w.w = pk_rne(kx[c*8+6], kx[c*8+7]);
            *reinterpret_cast<uint4*>(&Ks[t*40 + c*8]) = w;
        }
        #pragma unroll
        for (int d = 0; d < 32; d++) Vt[d*264 + t] = f16b(vx[d]);

        float w = __expf(-E[((size_t)bh << 8) + t]);
        ws[t] = w;
        float v = w;
        #pragma unroll
        for (int off = 32; off > 0; off >>= 1) v += __shfl_down(v, off);
        if ((tid & 63) == 0) red[tid >> 6] = v;
    }
    __syncthreads();
    const float psum = red[0] + red[1] + red[2] + red[3];

    // ---- pv[d] = sum_t w_t V[t][d] ---------------------------------------
    {
        int d = tid & 31, ch = tid >> 5;
        float acc = 0.f;
        #pragma unroll
        for (int tb = 0; tb < 4; tb++) {
            U4H8 hv;
            hv.u = *reinterpret_cast<const uint4*>(&Vt[d*264 + ch*32 + tb*8]);
            #pragma unroll
            for (int j = 0; j < 8; j++)
                acc = fmaf(ws[ch*32 + tb*8 + j], (float)hv.h[j], acc);
        }
        pvp[ch][d] = acc;
    }
    __syncthreads();
    if (tid < 32) {
        float s = 0.f;
        #pragma unroll
        for (int i = 0; i < 8; i++) s += pvp[i][tid];
        pvs[tid] = s;
    }
    __syncthreads();

    // ---- main: wave wv handles q-tile q0 = hb*128 + wv*32 -----------------
    const int lane = tid & 63, wv = tid >> 6;
    const int hh2 = lane >> 5, lq = lane & 31;
    const float g = 1.f / (1.f + __expf(-gate[h]));
    const float c2 = g / psum;
    const int q0 = hb*128 + wv*32;

    // Q fragments: hi+lo fp16 split (exact)
    U4H8 qh[2], ql[2];
    const float* qrow = Q + base + (size_t)(q0 + lq) * DD;
    #pragma unroll
    for (int ks = 0; ks < 2; ks++) {
        float4 a = *reinterpret_cast<const float4*>(qrow + ks*16 + hh2*8);
        float4 c = *reinterpret_cast<const float4*>(qrow + ks*16 + hh2*8 + 4);
        float e[8] = {a.x,a.y,a.z,a.w,c.x,c.y,c.z,c.w};
        split8f(e, qh[ks].u, ql[ks].u);
    }

    f32x16 acco;
    #pragma unroll
    for (int r = 0; r < 16; r++) acco[r] = 0.f;
    float rowsum = 0.f;

    #pragma unroll
    for (int tt = 0; tt < 8; tt++) {
        // S^T tile: K single x (Qh + Ql)
        f32x16 accs;
        #pragma unroll
        for (int r = 0; r < 16; r++) accs[r] = 0.f;
        const int trow = tt*32 + lq;
        __builtin_amdgcn_s_setprio(1);
        #pragma unroll
        for (int ks = 0; ks < 2; ks++) {
            U4H8 kf;
            kf.u = *reinterpret_cast<const uint4*>(&Ks[trow*40 + ks*16 + hh2*8]);
            accs = mfma16f(kf.h, qh[ks].h, accs);
            accs = mfma16f(kf.h, ql[ks].h, accs);
        }
        __builtin_amdgcn_s_setprio(0);
        // P = exp(S*scale): split hi+lo fp16, packed
        u32 PH[8], PL[8];
        #pragma unroll
        for (int j = 0; j < 8; j++) {
            float p0 = __expf(accs[2*j]   * SCALE);
            float p1 = __expf(accs[2*j+1] * SCALE);
            rowsum += p0 + p1;
            pksplit2(p0, p1, PH[j], PL[j]);
        }
        // PV: B-frag from C-regs via shfl_xor(32) half-swap + select
        #pragma unroll
        for (int ks = 0; ks < 2; ks++) {
            u32 HA0 = PH[ks*4+0], HA1 = PH[ks*4+1];
            u32 HB0 = PH[ks*4+2], HB1 = PH[ks*4+3];
            u32 LA0 = PL[ks*4+0], LA1 = PL[ks*4+1];
            u32 LB0 = PL[ks*4+2], LB1 = PL[ks*4+3];
            u32 XA0 = (u32)__shfl_xor((int)HA0, 32);
            u32 XA1 = (u32)__shfl_xor((int)HA1, 32);
            u32 XB0 = (u32)__shfl_xor((int)HB0, 32);
            u32 XB1 = (u32)__shfl_xor((int)HB1, 32);
            u32 YA0 = (u32)__shfl_xor((int)LA0, 32);
            u32 YA1 = (u32)__shfl_xor((int)LA1, 32);
            u32 YB0 = (u32)__shfl_xor((int)LB0, 32);
            u32 YB1 = (u32)__shfl_xor((int)LB1, 32);
            U4H8 bhf, blf, vf;
            bhf.u = make_uint4(hh2 ? XB0 : HA0, hh2 ? XB1 : HA1,
                               hh2 ? HB0 : XA0, hh2 ? HB1 : XA1);
            blf.u = make_uint4(hh2 ? YB0 : LA0, hh2 ? YB1 : LA1,
                               hh2 ? LB0 : YA0, hh2 ? LB1 : YA1);
            vf.u = *reinterpret_cast<const uint4*>(
                &Vt[lq*264 + tt*32 + ks*16 + hh2*8]);
            __builtin_amdgcn_s_setprio(1);
            acco = mfma16f(vf.h, bhf.h, acco);
            acco = mfma16f(vf.h, blf.h, acco);
            __builtin_amdgcn_s_setprio(0);
        }
    }

    rowsum += __shfl_xor(rowsum, 32);
    const float c1 = (1.f - g) / rowsum;
    float* orow = O + base + (size_t)(q0 + lq) * DD;
    #pragma unroll
    for (int r = 0; r < 16; r++) {
        int d = (r & 3) + 8*(r >> 2) + 4*hh2;
        orow[d] = c1 * acco[r] + c2 * pvs[d];
    }
}

// ---------------------------------------------------------------------------
extern "C" void kernel_launch(void* const* d_in, const int* in_sizes, int n_in,
                              void* d_out, int out_size, void* d_ws, size_t ws_size,
                              hipStream_t stream) {
    const float* x    = (const float*)d_in[0];
    const float* pos  = (const float*)d_in[1];
    const float* Wq   = (const float*)d_in[2];
    const float* Wk   = (const float*)d_in[3];
    const float* pw1  = (const float*)d_in[4];
    const float* pb1  = (const float*)d_in[5];
    const float* pw2  = (const float*)d_in[6];
    const float* pb2  = (const float*)d_in[7];
    const float* hw   = (const float*)d_in[8];
    // d_in[9] = head_b: cancels in softmax over t -> unused
    const float* gate = (const float*)d_in[10];
    const float* vemb = (const float*)d_in[11];
    const float* ow   = (const float*)d_in[12];
    const float* ob   = (const float*)d_in[13];
    float* out = (float*)d_out;

    const size_t NBS = (size_t)MROWS * DD;      // 4194304
    float* Qb   = (float*)d_ws;
    float* Kbuf = Qb + NBS;
    float* Vbuf = Kbuf + NBS;
    float* Ob   = Vbuf + NBS;
    float* Eb   = Ob + NBS;                     // 131072 floats
    u16*  WHp  = (u16*)(Eb + 131072);           // stacked [1024][256] f16

    hipLaunchKernelGGL(prep, dim3(256 + MROWS/256), dim3(256), 0, stream,
                       Wq, Wk, vemb, ow, WHp,
                       pos, pw1, pb1, pw2, pb2, hw, Eb);
    hipLaunchKernelGGL((gemm_mfma<true>), dim3(6, MROWS/128), dim3(256), 0, stream,
                       x, WHp, nullptr, Qb, Kbuf, Vbuf, 0);
    hipLaunchKernelGGL(attn_kernel, dim3(BB*HH*2), dim3(256), 0, stream,
                       Qb, Kbuf, Vbuf, Eb, gate, Ob);
    hipLaunchKernelGGL((gemm_mfma<false>), dim3(2, MROWS/128), dim3(256), 0, stream,
                       Ob, WHp, ob, out, out, out, 768);
}